// Round 8
// baseline (383.911 us; speedup 1.0000x reference)
//
#include <hip/hip_runtime.h>
#include <hip/hip_bf16.h>
#include <math.h>

#define NODES 30000
#define WAVE 64
#define SCAN_T 1024
#define SCAN_CH 32
#define SCAN_CAP (SCAN_T * SCAN_CH)   // 32768 >= NODES, branchless scan

typedef __attribute__((ext_vector_type(8))) short short8b;   // 8 bf16 (4 VGPRs)
typedef __attribute__((ext_vector_type(4))) float floatx4;   // MFMA C/D

static __device__ __forceinline__ float lrelu(float x) {
    return (x > 0.f) ? x : 0.2f * x;
}

// fp32 -> bf16 round-to-nearest-even
static __device__ __forceinline__ unsigned short f2bf(float f) {
    union { float f; unsigned u; } v; v.f = f;
    unsigned r = v.u + 0x7FFF + ((v.u >> 16) & 1);
    return (unsigned short)(r >> 16);
}

// ---------------------------------------------------------------------------
// MFMA GEMM: out[n, z*M + ct*16 + c] = Xb[n, z*K + k] @ Wb[z*M + m, k]^T
// bf16 inputs, fp32 accumulate. One 16x16 C tile per wave, LDS-free:
//   A frag: lane l -> row (l&15), k = (l>>4)*8 + 0..7  (16B contiguous)
//   B frag: lane l -> col (l&15), k = (l>>4)*8 + 0..7  (W row-major = W^T cols)
//   C frag: col = lane&15, row = (lane>>4)*4 + i       (m89-verified)
// grid = (ceil(N/64), M/16, heads). Optional fused attention dots via atomics.
// ---------------------------------------------------------------------------
template <int K, int M, int OUT_BF16, int RELU, int DOTS>
__global__ __launch_bounds__(256) void gemm_mfma(
    const unsigned short* __restrict__ Xb, int ldx,
    const unsigned short* __restrict__ Wb,
    const float* __restrict__ bias,
    void* __restrict__ outv, int ldc,
    const float* __restrict__ att_s, const float* __restrict__ att_d,
    float* __restrict__ as_out, float* __restrict__ ad_out,
    const int* __restrict__ flag, int Nrows)
{
    if (*flag == 0) return;                 // GAT path only
    constexpr int KC = K / 32;
    const int w    = threadIdx.x >> 6;
    const int lane = threadIdx.x & 63;
    const int z    = blockIdx.z;
    const int ct   = blockIdx.y;
    const int rowBase = blockIdx.x * 64 + w * 16;

    const int lr = lane & 15;
    const int lk = (lane >> 4) * 8;

    const int arow = min(rowBase + lr, Nrows - 1);
    const unsigned short* ap = Xb + (size_t)arow * ldx + z * K + lk;
    short8b a[KC];
#pragma unroll
    for (int kc = 0; kc < KC; kc++)
        a[kc] = *reinterpret_cast<const short8b*>(ap + kc * 32);

    const unsigned short* bp = Wb + (size_t)(z * M + ct * 16 + lr) * K + lk;
    short8b b[KC];
#pragma unroll
    for (int kc = 0; kc < KC; kc++)
        b[kc] = *reinterpret_cast<const short8b*>(bp + kc * 32);

    floatx4 c = {0.f, 0.f, 0.f, 0.f};
#pragma unroll
    for (int kc = 0; kc < KC; kc++)
        c = __builtin_amdgcn_mfma_f32_16x16x32_bf16(a[kc], b[kc], c, 0, 0, 0);

    const int colg = z * M + ct * 16 + lr;
    const float bv = bias ? bias[colg] : 0.f;

#pragma unroll
    for (int i = 0; i < 4; i++) {
        int r = rowBase + (lane >> 4) * 4 + i;
        float v = c[i] + bv;
        if (RELU) v = fmaxf(v, 0.f);
        if (r < Nrows) {
            if (OUT_BF16)
                ((unsigned short*)outv)[(size_t)r * ldc + colg] = f2bf(v);
            else
                ((float*)outv)[(size_t)r * ldc + colg] = v;
        }
    }

    if (DOTS) {  // heads==1: partial row-dot over this tile's 16 cols -> atomic
        const float as_v = att_s[colg];
        const float ad_v = att_d[colg];
#pragma unroll
        for (int i = 0; i < 4; i++) {
            int r = rowBase + (lane >> 4) * 4 + i;
            float ps = c[i] * as_v;
            float pd = c[i] * ad_v;
#pragma unroll
            for (int off = 8; off; off >>= 1) {
                ps += __shfl_xor(ps, off);
                pd += __shfl_xor(pd, off);
            }
            if (lr == 0 && r < Nrows) {
                atomicAdd(&as_out[r], ps);
                atomicAdd(&ad_out[r], pd);
            }
        }
    }
}

// ---------------------------------------------------------------------------
// fp32 GEMM (dense / use_neighbors==0 path only) — unchanged from round 7.
// ---------------------------------------------------------------------------
__global__ __launch_bounds__(256) void gemm_xwt(
    const float* __restrict__ X, int lda, const float* __restrict__ W,
    const float* __restrict__ bias, float* __restrict__ out, int ldc,
    int Nrows, int M, int K, int relu,
    const int* __restrict__ flag, int wantFlag)
{
    if (((*flag != 0) ? 1 : 0) != wantFlag) return;

    const int z = blockIdx.z;
    X += (size_t)z * K;
    W += (size_t)z * M * K;
    if (bias) bias += (size_t)z * M;
    out += (size_t)z * M;

    __shared__ float As[16][68];
    __shared__ float Bs[16][68];

    const int t  = threadIdx.x;
    const int tx = t & 15;
    const int ty = t >> 4;
    const int rowBase = blockIdx.y * 64;
    const int colBase = blockIdx.x * 64;

    float acc[4][4];
#pragma unroll
    for (int i = 0; i < 4; i++)
#pragma unroll
        for (int j = 0; j < 4; j++) acc[i][j] = 0.f;

    const int r_ld = t >> 2;
    const int k_ld = (t & 3) * 4;

    for (int kt = 0; kt < K; kt += 16) {
        float4 av = make_float4(0.f, 0.f, 0.f, 0.f);
        int grow = rowBase + r_ld;
        if (grow < Nrows)
            av = *reinterpret_cast<const float4*>(&X[(size_t)grow * lda + kt + k_ld]);
        As[k_ld + 0][r_ld] = av.x;
        As[k_ld + 1][r_ld] = av.y;
        As[k_ld + 2][r_ld] = av.z;
        As[k_ld + 3][r_ld] = av.w;
        float4 bv = make_float4(0.f, 0.f, 0.f, 0.f);
        int gm = colBase + r_ld;
        if (gm < M)
            bv = *reinterpret_cast<const float4*>(&W[(size_t)gm * K + kt + k_ld]);
        Bs[k_ld + 0][r_ld] = bv.x;
        Bs[k_ld + 1][r_ld] = bv.y;
        Bs[k_ld + 2][r_ld] = bv.z;
        Bs[k_ld + 3][r_ld] = bv.w;
        __syncthreads();

#pragma unroll
        for (int kk = 0; kk < 16; ++kk) {
            const float4 a = *reinterpret_cast<const float4*>(&As[kk][ty * 4]);
            const float4 b = *reinterpret_cast<const float4*>(&Bs[kk][tx * 4]);
            acc[0][0] += a.x * b.x; acc[0][1] += a.x * b.y; acc[0][2] += a.x * b.z; acc[0][3] += a.x * b.w;
            acc[1][0] += a.y * b.x; acc[1][1] += a.y * b.y; acc[1][2] += a.y * b.z; acc[1][3] += a.y * b.w;
            acc[2][0] += a.z * b.x; acc[2][1] += a.z * b.y; acc[2][2] += a.z * b.z; acc[2][3] += a.z * b.w;
            acc[3][0] += a.w * b.x; acc[3][1] += a.w * b.y; acc[3][2] += a.w * b.z; acc[3][3] += a.w * b.w;
        }
        __syncthreads();
    }

#pragma unroll
    for (int i = 0; i < 4; i++) {
        int row = rowBase + ty * 4 + i;
        if (row >= Nrows) continue;
        int col0 = colBase + tx * 4;
        if (col0 >= M) continue;
        float4 v = make_float4(acc[i][0], acc[i][1], acc[i][2], acc[i][3]);
        if (bias) {
            v.x += bias[col0 + 0]; v.y += bias[col0 + 1];
            v.z += bias[col0 + 2]; v.w += bias[col0 + 3];
        }
        if (relu) {
            v.x = fmaxf(v.x, 0.f); v.y = fmaxf(v.y, 0.f);
            v.z = fmaxf(v.z, 0.f); v.w = fmaxf(v.w, 0.f);
        }
        *reinterpret_cast<float4*>(&out[(size_t)row * ldc + col0]) = v;
    }
}

// ---------------------------------------------------------------------------
// Convert the four weight matrices fp32 -> bf16 (one launch).
// ---------------------------------------------------------------------------
__global__ void cvt_bf16(const float* __restrict__ s0, unsigned short* __restrict__ d0, int n0,
                         const float* __restrict__ s1, unsigned short* __restrict__ d1, int n1,
                         const float* __restrict__ s2, unsigned short* __restrict__ d2, int n2,
                         const float* __restrict__ s3, unsigned short* __restrict__ d3, int n3,
                         const int* __restrict__ flag)
{
    if (*flag == 0) return;
    int i = blockIdx.x * blockDim.x + threadIdx.x;
    if (i < n0) { d0[i] = f2bf(s0[i]); return; }
    i -= n0;
    if (i < n1) { d1[i] = f2bf(s1[i]); return; }
    i -= n1;
    if (i < n2) { d2[i] = f2bf(s2[i]); return; }
    i -= n2;
    if (i < n3) d3[i] = f2bf(s3[i]);
}

__global__ void zero_f2(float* __restrict__ a, float* __restrict__ b, int n,
                        const int* __restrict__ flag)
{
    if (*flag == 0) return;
    int i = blockIdx.x * blockDim.x + threadIdx.x;
    if (i < n) { a[i] = 0.f; b[i] = 0.f; }
}

// ---------------------------------------------------------------------------
// Fold attention vectors into input space: u[h,k] = sum_f att[h,f] * W[h*F+f, k]
// ---------------------------------------------------------------------------
template <int HH, int F, int K>
__global__ __launch_bounds__(256) void fold_att(
    const float* __restrict__ W, const float* __restrict__ as_,
    const float* __restrict__ ad_, float* __restrict__ us,
    float* __restrict__ ud, const int* __restrict__ flag)
{
    if (*flag == 0) return;
    const int b   = blockIdx.x;        // 0 .. 2*HH-1
    const int sel = b / HH;
    const int h   = b % HH;
    const float* att = sel ? ad_ : as_;
    float* uo = sel ? ud : us;

    constexpr int NG = 256 / K;
    const int k  = threadIdx.x % K;
    const int fg = threadIdx.x / K;

    float s = 0.f;
#pragma unroll
    for (int f = fg; f < F; f += NG)
        s += att[h * F + f] * W[(size_t)(h * F + f) * K + k];

    __shared__ float red[256];
    red[threadIdx.x] = s;
    __syncthreads();
    if (fg == 0) {
        float tot = s;
#pragma unroll
        for (int g = 1; g < NG; g++) tot += red[g * K + k];
        uo[h * K + k] = tot;
    }
}

// ---------------------------------------------------------------------------
// a_s[n,h] = feat[n,:] . u_s[h,:]  (and a_d).  64/K nodes per wave.
// ---------------------------------------------------------------------------
template <int K, int HH>
__global__ __launch_bounds__(256) void att_from_x(
    const float* __restrict__ xin, const float* __restrict__ us,
    const float* __restrict__ ud, float* __restrict__ as_out,
    float* __restrict__ ad_out, const int* __restrict__ flag)
{
    if (*flag == 0) return;
    constexpr int NPW = WAVE / K;
    const int wid  = threadIdx.x >> 6;
    const int lane = threadIdx.x & 63;
    const int sub  = lane / K;
    const int col  = lane % K;
    const int node = (blockIdx.x * 4 + wid) * NPW + sub;

    float v = 0.f;
    if (node < NODES) v = xin[(size_t)node * K + col];
    float ps[HH], pd[HH];
#pragma unroll
    for (int h = 0; h < HH; h++) {
        ps[h] = v * us[h * K + col];
        pd[h] = v * ud[h * K + col];
    }
#pragma unroll
    for (int off = K / 2; off; off >>= 1) {
#pragma unroll
        for (int h = 0; h < HH; h++) {
            ps[h] += __shfl_xor(ps[h], off);
            pd[h] += __shfl_xor(pd[h], off);
        }
    }
    if (col == 0 && node < NODES) {
#pragma unroll
        for (int h = 0; h < HH; h++) {
            as_out[node * HH + h] = ps[h];
            ad_out[node * HH + h] = pd[h];
        }
    }
}

// ---------------------------------------------------------------------------
// Fused GAT aggregation of RAW features (layers 1/3) -> bf16 output.
// Fast path (deg <= 64): one edge per lane, softmax in registers; gather loop
// has wave-uniform trip count (shfl source lanes always active).
// ---------------------------------------------------------------------------
template <int K, int HH>
__global__ __launch_bounds__(256) void gat_aggr_x(
    const float* __restrict__ xin, const float* __restrict__ as_,
    const float* __restrict__ ad_, const int* __restrict__ rowptr,
    const int* __restrict__ csr_src, unsigned short* __restrict__ aggb,
    const int* __restrict__ flag)
{
    if (*flag == 0) return;
    const int node = blockIdx.x * 4 + (threadIdx.x >> 6);
    const int lane = threadIdx.x & 63;
    if (node >= NODES) return;

    const int beg = rowptr[node], end = rowptr[node + 1];
    const int deg = end - beg;

    float adv[HH];
#pragma unroll
    for (int h = 0; h < HH; h++) adv[h] = ad_[node * HH + h];

    float wl[HH];
    float mx[HH], rden[HH];
    const bool fast = (deg <= WAVE);

    if (fast) {
        float e[HH];
        int i = beg + lane;
        if (i < end) {
            int s = csr_src[i];
#pragma unroll
            for (int h = 0; h < HH; h++)
                e[h] = lrelu(as_[s * HH + h] + adv[h]);
        } else {
#pragma unroll
            for (int h = 0; h < HH; h++) e[h] = -1e30f;
        }
#pragma unroll
        for (int h = 0; h < HH; h++) {
            mx[h] = e[h];
#pragma unroll
            for (int off = 32; off; off >>= 1)
                mx[h] = fmaxf(mx[h], __shfl_xor(mx[h], off));
            float ex = __expf(e[h] - mx[h]);
            wl[h] = ex;
            float dn = ex;
#pragma unroll
            for (int off = 32; off; off >>= 1)
                dn += __shfl_xor(dn, off);
            rden[h] = 1.f / dn;
        }
    } else {
        float den[HH];
#pragma unroll
        for (int h = 0; h < HH; h++) { mx[h] = -1e30f; den[h] = 0.f; }
        for (int i = beg + lane; i < end; i += WAVE) {
            int s = csr_src[i];
#pragma unroll
            for (int h = 0; h < HH; h++)
                mx[h] = fmaxf(mx[h], lrelu(as_[s * HH + h] + adv[h]));
        }
#pragma unroll
        for (int h = 0; h < HH; h++)
#pragma unroll
            for (int off = 32; off; off >>= 1)
                mx[h] = fmaxf(mx[h], __shfl_xor(mx[h], off));
        for (int i = beg + lane; i < end; i += WAVE) {
            int s = csr_src[i];
#pragma unroll
            for (int h = 0; h < HH; h++)
                den[h] += __expf(lrelu(as_[s * HH + h] + adv[h]) - mx[h]);
        }
#pragma unroll
        for (int h = 0; h < HH; h++) {
#pragma unroll
            for (int off = 32; off; off >>= 1)
                den[h] += __shfl_xor(den[h], off);
            rden[h] = 1.f / den[h];
        }
    }

    constexpr int LPG = K / 4;
    constexpr int GR  = WAVE / LPG;
    const int esub = lane / LPG;
    const int c4   = lane % LPG;

    float4 acc[HH];
#pragma unroll
    for (int h = 0; h < HH; h++) acc[h] = make_float4(0.f, 0.f, 0.f, 0.f);

    if (fast) {
        const int iters = (deg + GR - 1) / GR;   // wave-uniform
        for (int it = 0; it < iters; ++it) {
            const int i = beg + it * GR + esub;
            const bool valid = (i < end);
            const int srcl = valid ? (i - beg) : 0;
            float w[HH];
#pragma unroll
            for (int h = 0; h < HH; h++)
                w[h] = __shfl(wl[h], srcl);
            if (valid) {
                int s = csr_src[i];
                float4 xv = *reinterpret_cast<const float4*>(&xin[(size_t)s * K + c4 * 4]);
#pragma unroll
                for (int h = 0; h < HH; h++) {
                    acc[h].x += xv.x * w[h];
                    acc[h].y += xv.y * w[h];
                    acc[h].z += xv.z * w[h];
                    acc[h].w += xv.w * w[h];
                }
            }
        }
    } else {
        for (int i = beg + esub; i < end; i += GR) {
            int s = csr_src[i];
            float w[HH];
#pragma unroll
            for (int h = 0; h < HH; h++)
                w[h] = __expf(lrelu(as_[s * HH + h] + adv[h]) - mx[h]);
            float4 xv = *reinterpret_cast<const float4*>(&xin[(size_t)s * K + c4 * 4]);
#pragma unroll
            for (int h = 0; h < HH; h++) {
                acc[h].x += xv.x * w[h];
                acc[h].y += xv.y * w[h];
                acc[h].z += xv.z * w[h];
                acc[h].w += xv.w * w[h];
            }
        }
    }
#pragma unroll
    for (int off = LPG; off < WAVE; off <<= 1) {
#pragma unroll
        for (int h = 0; h < HH; h++) {
            acc[h].x += __shfl_xor(acc[h].x, off);
            acc[h].y += __shfl_xor(acc[h].y, off);
            acc[h].z += __shfl_xor(acc[h].z, off);
            acc[h].w += __shfl_xor(acc[h].w, off);
        }
    }
    if (esub == 0) {
#pragma unroll
        for (int h = 0; h < HH; h++) {
            ushort4 o;
            o.x = f2bf(acc[h].x * rden[h]);
            o.y = f2bf(acc[h].y * rden[h]);
            o.z = f2bf(acc[h].z * rden[h]);
            o.w = f2bf(acc[h].w * rden[h]);
            *reinterpret_cast<ushort4*>(&aggb[(size_t)node * (HH * K) + h * K + c4 * 4]) = o;
        }
    }
}

// ---------------------------------------------------------------------------
// Fused GAT aggregation of PROJECTED features (layers 2/4), +bias (+relu).
// Unchanged from round 7 (fp32 in/out).
// ---------------------------------------------------------------------------
template <int HF, int RELU>
__global__ __launch_bounds__(256) void gat_aggr_h(
    const float* __restrict__ hsrc, const float* __restrict__ as_,
    const float* __restrict__ ad_, const int* __restrict__ rowptr,
    const int* __restrict__ csr_src, const float* __restrict__ bias,
    float* __restrict__ out, const int* __restrict__ flag)
{
    if (*flag == 0) return;
    const int node = blockIdx.x * 4 + (threadIdx.x >> 6);
    const int lane = threadIdx.x & 63;
    if (node >= NODES) return;

    const int beg = rowptr[node], end = rowptr[node + 1];
    const int deg = end - beg;
    const float adv = ad_[node];

    float wl, mx, rden;
    const bool fast = (deg <= WAVE);

    if (fast) {
        int i = beg + lane;
        float e = -1e30f;
        if (i < end) {
            int s = csr_src[i];
            e = lrelu(as_[s] + adv);
        }
        mx = e;
#pragma unroll
        for (int off = 32; off; off >>= 1)
            mx = fmaxf(mx, __shfl_xor(mx, off));
        wl = __expf(e - mx);
        float dn = wl;
#pragma unroll
        for (int off = 32; off; off >>= 1)
            dn += __shfl_xor(dn, off);
        rden = 1.f / dn;
    } else {
        mx = -1e30f;
        float den = 0.f;
        for (int i = beg + lane; i < end; i += WAVE) {
            int s = csr_src[i];
            mx = fmaxf(mx, lrelu(as_[s] + adv));
        }
#pragma unroll
        for (int off = 32; off; off >>= 1)
            mx = fmaxf(mx, __shfl_xor(mx, off));
        for (int i = beg + lane; i < end; i += WAVE) {
            int s = csr_src[i];
            den += __expf(lrelu(as_[s] + adv) - mx);
        }
#pragma unroll
        for (int off = 32; off; off >>= 1)
            den += __shfl_xor(den, off);
        rden = 1.f / den;
        wl = 0.f;
    }

    constexpr int LPG = HF / 4;
    constexpr int GR  = WAVE / LPG;
    const int esub = lane / LPG;
    const int c4   = lane % LPG;

    float4 acc = make_float4(0.f, 0.f, 0.f, 0.f);
    if (fast) {
        const int iters = (deg + GR - 1) / GR;   // wave-uniform
        for (int it = 0; it < iters; ++it) {
            const int i = beg + it * GR + esub;
            const bool valid = (i < end);
            const int srcl = valid ? (i - beg) : 0;
            float w = __shfl(wl, srcl);
            if (valid) {
                int s = csr_src[i];
                float4 hv = *reinterpret_cast<const float4*>(&hsrc[(size_t)s * HF + c4 * 4]);
                acc.x += hv.x * w; acc.y += hv.y * w; acc.z += hv.z * w; acc.w += hv.w * w;
            }
        }
    } else {
        for (int i = beg + esub; i < end; i += GR) {
            int s = csr_src[i];
            float w = __expf(lrelu(as_[s] + adv) - mx);
            float4 hv = *reinterpret_cast<const float4*>(&hsrc[(size_t)s * HF + c4 * 4]);
            acc.x += hv.x * w; acc.y += hv.y * w; acc.z += hv.z * w; acc.w += hv.w * w;
        }
    }
#pragma unroll
    for (int off = LPG; off < WAVE; off <<= 1) {
        acc.x += __shfl_xor(acc.x, off);
        acc.y += __shfl_xor(acc.y, off);
        acc.z += __shfl_xor(acc.z, off);
        acc.w += __shfl_xor(acc.w, off);
    }
    if (esub == 0) {
        float4 bv = *reinterpret_cast<const float4*>(&bias[c4 * 4]);
        float4 o = make_float4(acc.x * rden + bv.x, acc.y * rden + bv.y,
                               acc.z * rden + bv.z, acc.w * rden + bv.w);
        if (RELU) {
            o.x = fmaxf(o.x, 0.f); o.y = fmaxf(o.y, 0.f);
            o.z = fmaxf(o.z, 0.f); o.w = fmaxf(o.w, 0.f);
        }
        *reinterpret_cast<float4*>(&out[(size_t)node * HF + c4 * 4]) = o;
    }
}

// ---------------------------------------------------------------------------
// CSR build kernels
// ---------------------------------------------------------------------------
__global__ void zero_int(int* __restrict__ p, int n, const int* __restrict__ flag)
{
    if (*flag == 0) return;
    for (int i = blockIdx.x * blockDim.x + threadIdx.x; i < n; i += gridDim.x * blockDim.x)
        p[i] = 0;
}

__global__ void count_deg(const int* __restrict__ ei, int* __restrict__ deg,
                          int E_, int Nn, const int* __restrict__ flag)
{
    if (*flag == 0) return;
    int e = blockIdx.x * blockDim.x + threadIdx.x;
    int tot = E_ + Nn;
    if (e >= tot) return;
    int dst = (e < E_) ? ei[E_ + e] : (e - E_);
    atomicAdd(&deg[dst], 1);
}

__global__ __launch_bounds__(SCAN_T) void scan_deg(
    const int* __restrict__ deg, int* __restrict__ rowptr,
    int* __restrict__ cursor, const int* __restrict__ flag)
{
    if (*flag == 0) return;
    __shared__ int sums[SCAN_T];
    const int t = threadIdx.x;
    const int base = t * SCAN_CH;

    int v[SCAN_CH];
    const int4* dp = reinterpret_cast<const int4*>(deg + base);
#pragma unroll
    for (int j = 0; j < SCAN_CH / 4; j++) {
        int4 q = dp[j];
        v[4 * j + 0] = q.x; v[4 * j + 1] = q.y;
        v[4 * j + 2] = q.z; v[4 * j + 3] = q.w;
    }
    int s = 0;
#pragma unroll
    for (int j = 0; j < SCAN_CH; j++) s += v[j];
    sums[t] = s;
    __syncthreads();
    for (int off = 1; off < SCAN_T; off <<= 1) {
        int x = (t >= off) ? sums[t - off] : 0;
        __syncthreads();
        sums[t] += x;
        __syncthreads();
    }
    int run = sums[t] - s;
    if (t == 0) rowptr[0] = 0;
#pragma unroll
    for (int j = 0; j < SCAN_CH; j++) {
        cursor[base + j] = run;
        run += v[j];
        rowptr[base + j + 1] = run;
    }
}

__global__ void scatter_edges(const int* __restrict__ ei, int* __restrict__ cursor,
                              int* __restrict__ csr_src, int E_, int Nn,
                              const int* __restrict__ flag)
{
    if (*flag == 0) return;
    int e = blockIdx.x * blockDim.x + threadIdx.x;
    int tot = E_ + Nn;
    if (e >= tot) return;
    int src, dst;
    if (e < E_) { src = ei[e]; dst = ei[E_ + e]; }
    else        { src = e - E_; dst = src; }
    int pos = atomicAdd(&cursor[dst], 1);
    csr_src[pos] = src;
}

// ---------------------------------------------------------------------------
extern "C" void kernel_launch(void* const* d_in, const int* in_sizes, int n_in,
                              void* d_out, int out_size, void* d_ws, size_t ws_size,
                              hipStream_t stream)
{
    const float* x    = (const float*)d_in[0];
    const int*   ei   = (const int*)d_in[1];
    const int*   flag = (const int*)d_in[2];
    const float* W1 = (const float*)d_in[3];
    const float* as1 = (const float*)d_in[4];
    const float* ad1 = (const float*)d_in[5];
    const float* b1 = (const float*)d_in[6];
    const float* W2 = (const float*)d_in[7];
    const float* as2 = (const float*)d_in[8];
    const float* ad2 = (const float*)d_in[9];
    const float* b2 = (const float*)d_in[10];
    const float* W3 = (const float*)d_in[11];
    const float* as3 = (const float*)d_in[12];
    const float* ad3 = (const float*)d_in[13];
    const float* b3 = (const float*)d_in[14];
    const float* W4 = (const float*)d_in[15];
    const float* as4 = (const float*)d_in[16];
    const float* ad4 = (const float*)d_in[17];
    const float* b4 = (const float*)d_in[18];
    const float* el1w = (const float*)d_in[19];
    const float* el1b = (const float*)d_in[20];
    const float* el2w = (const float*)d_in[21];
    const float* el2b = (const float*)d_in[22];
    const float* dl1w = (const float*)d_in[23];
    const float* dl1b = (const float*)d_in[24];
    const float* dl2w = (const float*)d_in[25];
    const float* dl2b = (const float*)d_in[26];

    const int E_   = in_sizes[1] / 2;
    const int Etot = E_ + NODES;

    char* base = (char*)d_ws;
    size_t off = 0;
    auto carve = [&](size_t bytes) -> void* {
        void* p = base + off;
        off = (off + bytes + 255) & ~(size_t)255;
        return p;
    };
    float* T0  = (float*)carve((size_t)NODES * 128 * 4);   // dense intermediate
    float* A   = (float*)carve((size_t)NODES * 256 * 4);   // dense intermediate
    float* T1  = (float*)carve((size_t)NODES * 64 * 4);    // h2 / h4 (fp32)
    float* Bz  = (float*)carve((size_t)NODES * 32 * 4);    // z (fp32)
    float* asb = (float*)carve((size_t)NODES * 2 * 4);
    float* adb = (float*)carve((size_t)NODES * 2 * 4);
    float* u1s = (float*)carve(2 * 64 * 4);
    float* u1d = (float*)carve(2 * 64 * 4);
    float* u3s = (float*)carve(2 * 32 * 4);
    float* u3d = (float*)carve(2 * 32 * 4);
    unsigned short* aggb = (unsigned short*)carve((size_t)NODES * 128 * 2);  // bf16 agg (L1/L3)
    unsigned short* Ab   = (unsigned short*)carve((size_t)NODES * 256 * 2);  // bf16 layer-1/3 out
    unsigned short* wb1  = (unsigned short*)carve(256 * 64 * 2);
    unsigned short* wb2  = (unsigned short*)carve(32 * 256 * 2);
    unsigned short* wb3  = (unsigned short*)carve(256 * 32 * 2);
    unsigned short* wb4  = (unsigned short*)carve(64 * 256 * 2);
    int* deg    = (int*)carve((size_t)SCAN_CAP * 4);
    int* rowptr = (int*)carve((size_t)(SCAN_CAP + 1) * 4);
    int* cursor = (int*)carve((size_t)SCAN_CAP * 4);
    int* csr    = (int*)carve((size_t)Etot * 4);
    (void)ws_size; (void)n_in; (void)out_size;

    float* outp = (float*)d_out;

    const int nodeBlocks = (NODES + 3) / 4;
    const int edgeBlocks = (Etot + 255) / 256;
    dim3 blk(256);
    const int rowTiles = (NODES + 63) / 64;   // 469

    // ---- CSR build + weight conversion ----
    zero_int<<<(SCAN_CAP + 255) / 256, 256, 0, stream>>>(deg, SCAN_CAP, flag);
    count_deg<<<edgeBlocks, 256, 0, stream>>>(ei, deg, E_, NODES, flag);
    scan_deg<<<1, SCAN_T, 0, stream>>>(deg, rowptr, cursor, flag);
    scatter_edges<<<edgeBlocks, 256, 0, stream>>>(ei, cursor, csr, E_, NODES, flag);
    cvt_bf16<<<(16384 + 8192 + 8192 + 16384 + 255) / 256, 256, 0, stream>>>(
        W1, wb1, 16384, W2, wb2, 8192, W3, wb3, 8192, W4, wb4, 16384, flag);

    // ---- Layer 1: GAT(64 -> 128 x 2 heads) + ReLU [aggregate-then-project] ----
    fold_att<2, 128, 64><<<4, 256, 0, stream>>>(W1, as1, ad1, u1s, u1d, flag);
    att_from_x<64, 2><<<nodeBlocks, blk, 0, stream>>>(x, u1s, u1d, asb, adb, flag);
    gat_aggr_x<64, 2><<<nodeBlocks, blk, 0, stream>>>(x, asb, adb, rowptr, csr, aggb, flag);
    gemm_mfma<64, 128, 1, 1, 0><<<dim3(rowTiles, 8, 2), blk, 0, stream>>>(
        aggb, 128, wb1, b1, Ab, 256, nullptr, nullptr, nullptr, nullptr, flag, NODES);

    // ---- Layer 2: GAT(256 -> 32, 1 head): MFMA gemm + fused atomic dots ----
    zero_f2<<<(NODES + 255) / 256, 256, 0, stream>>>(asb, adb, NODES, flag);
    gemm_mfma<256, 32, 0, 0, 1><<<dim3(rowTiles, 2, 1), blk, 0, stream>>>(
        Ab, 256, wb2, nullptr, T1, 32, as2, ad2, asb, adb, flag, NODES);
    gat_aggr_h<32, 0><<<nodeBlocks, blk, 0, stream>>>(T1, asb, adb, rowptr, csr, b2, Bz, flag);

    // ---- Layer 3: GAT(32 -> 128 x 2 heads) + ReLU [aggregate-then-project] ----
    fold_att<2, 128, 32><<<4, 256, 0, stream>>>(W3, as3, ad3, u3s, u3d, flag);
    att_from_x<32, 2><<<(NODES + 7) / 8, blk, 0, stream>>>(Bz, u3s, u3d, asb, adb, flag);
    gat_aggr_x<32, 2><<<nodeBlocks, blk, 0, stream>>>(Bz, asb, adb, rowptr, csr, aggb, flag);
    gemm_mfma<32, 128, 1, 1, 0><<<dim3(rowTiles, 8, 2), blk, 0, stream>>>(
        aggb, 64, wb3, b3, Ab, 256, nullptr, nullptr, nullptr, nullptr, flag, NODES);

    // ---- Layer 4: GAT(256 -> 64, 1 head): MFMA gemm + fused atomic dots ----
    zero_f2<<<(NODES + 255) / 256, 256, 0, stream>>>(asb, adb, NODES, flag);
    gemm_mfma<256, 64, 0, 0, 1><<<dim3(rowTiles, 4, 1), blk, 0, stream>>>(
        Ab, 256, wb4, nullptr, T1, 64, as4, ad4, asb, adb, flag, NODES);
    gat_aggr_h<64, 0><<<nodeBlocks, blk, 0, stream>>>(T1, asb, adb, rowptr, csr, b4, outp, flag);

    // ---- Dense path (use_neighbors == 0), fp32, unchanged ----
    gemm_xwt<<<dim3(2, rowTiles, 1), blk, 0, stream>>>(x,  64,  el1w, el1b, T0,   128, NODES, 128, 64, 1, flag, 0);
    gemm_xwt<<<dim3(1, rowTiles, 1), blk, 0, stream>>>(T0, 128, el2w, el2b, Bz,   32,  NODES, 32, 128, 0, flag, 0);
    gemm_xwt<<<dim3(2, rowTiles, 1), blk, 0, stream>>>(Bz, 32,  dl1w, dl1b, A,    128, NODES, 128, 32, 1, flag, 0);
    gemm_xwt<<<dim3(1, rowTiles, 1), blk, 0, stream>>>(A,  128, dl2w, dl2b, outp, 64,  NODES, 64, 128, 0, flag, 0);
}